// Round 2
// baseline (324.347 us; speedup 1.0000x reference)
//
#include <hip/hip_runtime.h>
#include <hip/hip_fp16.h>

// SpMM: out[r,:] = sum_{k: rows[k]==r} values[k] * weight[cols[k],:]  + bias
// Pipeline: [memset counts] -> convert_count (f32->f16 table + row histogram)
//           -> scan (offsets/cursor) -> scatter (row-sorted (col,val) pairs)
//           -> accum (4 waves/row, 16B/lane fp16 gathers, LDS cross-wave reduce).
// R1 evidence: accum = 76us, BW-bound at 3.4 TB/s fabric / 7.1 TB/s effective
// (MLP-insensitive). Total 320us => ~150+us hidden in preprocessing dispatches.
// R2: vectorize/NT the preprocessing (convert 16 floats/thread + NT stores,
// scan int4, scatter 4 nnz/thread); accum unchanged except NT pairs loads.

typedef float f4v __attribute__((ext_vector_type(4)));
typedef int   i4v __attribute__((ext_vector_type(4)));
typedef int   i2v __attribute__((ext_vector_type(2)));

// ---- Fused: weight f32->f16 (16 floats/thread, NT stores) + row histogram (int4) ----
__global__ void convert_count_kernel(const float* __restrict__ weight,
                                     __half* __restrict__ wf16, long long ngroups16,
                                     const int* __restrict__ rows,
                                     int* __restrict__ counts, int nnz) {
    long long i = (long long)blockIdx.x * blockDim.x + threadIdx.x;

    // Histogram: 4 rows per thread, vectorized read of rows[].
    int nquads = nnz >> 2;
    if (i < nquads) {
        i4v r = ((const i4v*)rows)[i];
        atomicAdd(&counts[r.x], 1);
        atomicAdd(&counts[r.y], 1);
        atomicAdd(&counts[r.z], 1);
        atomicAdd(&counts[r.w], 1);
    } else if (i == nquads) {
        for (int k = nquads * 4; k < nnz; ++k) atomicAdd(&counts[rows[k]], 1);
    }

    // Conversion: 16 floats per thread (64B read, 2x16B NT write).
    const f4v* w4 = (const f4v*)weight;
    f4v* dst = (f4v*)wf16;                     // one f4v = 8 halfs
    long long stride = (long long)gridDim.x * blockDim.x;
    for (long long g = i; g < ngroups16; g += stride) {
        f4v a = w4[4 * g + 0];
        f4v b = w4[4 * g + 1];
        f4v c = w4[4 * g + 2];
        f4v d = w4[4 * g + 3];
        union { __half2 h2[4]; f4v v; } u0, u1;
        u0.h2[0] = __floats2half2_rn(a.x, a.y);
        u0.h2[1] = __floats2half2_rn(a.z, a.w);
        u0.h2[2] = __floats2half2_rn(b.x, b.y);
        u0.h2[3] = __floats2half2_rn(b.z, b.w);
        u1.h2[0] = __floats2half2_rn(c.x, c.y);
        u1.h2[1] = __floats2half2_rn(c.z, c.w);
        u1.h2[2] = __floats2half2_rn(d.x, d.y);
        u1.h2[3] = __floats2half2_rn(d.z, d.w);
        __builtin_nontemporal_store(u0.v, &dst[2 * g]);
        __builtin_nontemporal_store(u1.v, &dst[2 * g + 1]);
    }
}

// ---- Exclusive scan over n_rows counts (1 block, 256 thr); offsets AND cursor ----
__global__ void scan_kernel(const int* __restrict__ counts, int* __restrict__ offsets,
                            int* __restrict__ cursor, int n_rows) {
    __shared__ int partial[256];
    const int t = threadIdx.x;
    const int per = (n_rows + 255) / 256;
    const int base = t * per;
    const bool vec = (base + per <= n_rows) && ((per & 3) == 0);

    int sum = 0;
    if (vec) {
        const i4v* c4 = (const i4v*)(counts + base);
        for (int j = 0; j < per / 4; ++j) {
            i4v q = c4[j];
            sum += q.x + q.y + q.z + q.w;
        }
    } else {
        for (int j = 0; j < per; ++j) {
            int idx = base + j;
            if (idx < n_rows) sum += counts[idx];
        }
    }
    partial[t] = sum;
    __syncthreads();
    for (int off = 1; off < 256; off <<= 1) {
        int v = 0;
        if (t >= off) v = partial[t - off];
        __syncthreads();
        if (t >= off) partial[t] += v;
        __syncthreads();
    }
    int run = (t == 0) ? 0 : partial[t - 1];
    if (vec) {
        const i4v* c4 = (const i4v*)(counts + base);
        i4v* o4 = (i4v*)(offsets + base);
        i4v* u4 = (i4v*)(cursor + base);
        for (int j = 0; j < per / 4; ++j) {
            i4v q = c4[j];
            i4v o;
            o.x = run; run += q.x;
            o.y = run; run += q.y;
            o.z = run; run += q.z;
            o.w = run; run += q.w;
            o4[j] = o;
            u4[j] = o;
        }
    } else {
        for (int j = 0; j < per; ++j) {
            int idx = base + j;
            if (idx < n_rows) {
                offsets[idx] = run;
                cursor[idx] = run;
                run += counts[idx];
            }
        }
    }
    if (t == 255) offsets[n_rows] = run;
}

// ---- Scatter nnz into row-sorted (col,val) pairs; 4 nnz/thread vectorized ----
__global__ void scatter_pairs_kernel(const int* __restrict__ rows, const int* __restrict__ cols,
                                     const float* __restrict__ values, int* __restrict__ cursor,
                                     int2* __restrict__ pairs, int nnz) {
    int i = blockIdx.x * blockDim.x + threadIdx.x;
    int nquads = nnz >> 2;
    if (i < nquads) {
        i4v r = ((const i4v*)rows)[i];
        i4v c = ((const i4v*)cols)[i];
        f4v v = ((const f4v*)values)[i];
        int p0 = atomicAdd(&cursor[r.x], 1);
        pairs[p0] = make_int2(c.x, __float_as_int(v.x));
        int p1 = atomicAdd(&cursor[r.y], 1);
        pairs[p1] = make_int2(c.y, __float_as_int(v.y));
        int p2 = atomicAdd(&cursor[r.z], 1);
        pairs[p2] = make_int2(c.z, __float_as_int(v.z));
        int p3 = atomicAdd(&cursor[r.w], 1);
        pairs[p3] = make_int2(c.w, __float_as_int(v.w));
    } else if (i == nquads) {
        for (int k = nquads * 4; k < nnz; ++k) {
            int p = atomicAdd(&cursor[rows[k]], 1);
            pairs[p] = make_int2(cols[k], __float_as_int(values[k]));
        }
    }
}

// ---- Accumulate: 4 waves per output row; wave covers all 512 cols (lane = 8 fp16) ----
__global__ __launch_bounds__(256) void accum_f16_kernel(
    const __half* __restrict__ wf16, const float* __restrict__ bias,
    const int* __restrict__ offsets, const int2* __restrict__ pairs,
    float* __restrict__ out, int out_f) {
    const int wave = threadIdx.x >> 6;
    const int lane = threadIdx.x & 63;
    const int row = blockIdx.x;
    const int start = offsets[row];
    const int end = offsets[row + 1];
    const int len = end - start;
    const int per = (len + 3) >> 2;           // nnz per wave
    int p = start + wave * per;
    int pe = p + per;
    if (pe > end) pe = end;
    if (p > end) p = end;

    const f4v* wbase = (const f4v*)wf16;      // one f4v = 8 halfs
    const i2v* pbase = (const i2v*)pairs;
    float acc[8] = {0.f, 0.f, 0.f, 0.f, 0.f, 0.f, 0.f, 0.f};

    for (; p + 4 <= pe; p += 4) {
        i2v e0 = __builtin_nontemporal_load(pbase + p);
        i2v e1 = __builtin_nontemporal_load(pbase + p + 1);
        i2v e2 = __builtin_nontemporal_load(pbase + p + 2);
        i2v e3 = __builtin_nontemporal_load(pbase + p + 3);
        f4v w0 = wbase[(long long)e0.x * 64 + lane];
        f4v w1 = wbase[(long long)e1.x * 64 + lane];
        f4v w2 = wbase[(long long)e2.x * 64 + lane];
        f4v w3 = wbase[(long long)e3.x * 64 + lane];
        float v0 = __int_as_float(e0.y);
        float v1 = __int_as_float(e1.y);
        float v2 = __int_as_float(e2.y);
        float v3 = __int_as_float(e3.y);
        const __half2* h0 = (const __half2*)&w0;
        const __half2* h1 = (const __half2*)&w1;
        const __half2* h2 = (const __half2*)&w2;
        const __half2* h3 = (const __half2*)&w3;
#pragma unroll
        for (int j = 0; j < 4; ++j) {
            float2 f0 = __half22float2(h0[j]);
            float2 f1 = __half22float2(h1[j]);
            float2 f2 = __half22float2(h2[j]);
            float2 f3 = __half22float2(h3[j]);
            acc[2 * j]     += v0 * f0.x + v1 * f1.x + v2 * f2.x + v3 * f3.x;
            acc[2 * j + 1] += v0 * f0.y + v1 * f1.y + v2 * f2.y + v3 * f3.y;
        }
    }
    for (; p < pe; ++p) {
        i2v e0 = __builtin_nontemporal_load(pbase + p);
        float v0 = __int_as_float(e0.y);
        f4v w0 = wbase[(long long)e0.x * 64 + lane];
        const __half2* h0 = (const __half2*)&w0;
#pragma unroll
        for (int j = 0; j < 4; ++j) {
            float2 f0 = __half22float2(h0[j]);
            acc[2 * j]     += v0 * f0.x;
            acc[2 * j + 1] += v0 * f0.y;
        }
    }

    // Cross-wave reduce: 4 x 512 f32 partials in LDS (8 KB).
    __shared__ float red[4][512];
    {
        float4* dstp = (float4*)&red[wave][lane * 8];
        dstp[0] = make_float4(acc[0], acc[1], acc[2], acc[3]);
        dstp[1] = make_float4(acc[4], acc[5], acc[6], acc[7]);
    }
    __syncthreads();
    const int c = threadIdx.x * 2;
    float s0 = red[0][c] + red[1][c] + red[2][c] + red[3][c];
    float s1 = red[0][c + 1] + red[1][c + 1] + red[2][c + 1] + red[3][c + 1];
    float2 b = *(const float2*)(bias + c);
    *(float2*)(out + (long long)row * out_f + c) = make_float2(s0 + b.x, s1 + b.y);
}

// ================= Fallback path (ws too small / shape mismatch): f32 scheme =================
__global__ void count_rows_kernel(const int* __restrict__ rows, int* __restrict__ counts, int nnz) {
    int i = blockIdx.x * blockDim.x + threadIdx.x;
    if (i < nnz) atomicAdd(&counts[rows[i]], 1);
}
__global__ void scatter_kernel(const int* __restrict__ rows, int* __restrict__ cursor,
                               int* __restrict__ perm, int nnz) {
    int i = blockIdx.x * blockDim.x + threadIdx.x;
    if (i < nnz) {
        int p = atomicAdd(&cursor[rows[i]], 1);
        perm[p] = i;
    }
}
__global__ void accum_kernel(const float* __restrict__ values, const float* __restrict__ weight,
                             const float* __restrict__ bias, const int* __restrict__ cols,
                             const int* __restrict__ offsets, const int* __restrict__ perm,
                             float* __restrict__ out, int out_f) {
    const int r = blockIdx.x;
    const int start = offsets[r];
    const int end = offsets[r + 1];
    const int step = blockDim.x * 4;
    for (int base = threadIdx.x * 4; base < out_f; base += step) {
        float4 acc = make_float4(0.f, 0.f, 0.f, 0.f);
        for (int p = start; p < end; ++p) {
            int k = perm[p];
            float v = values[k];
            long long c = cols[k];
            float4 w = *(const float4*)(weight + c * (long long)out_f + base);
            acc.x += v * w.x; acc.y += v * w.y; acc.z += v * w.z; acc.w += v * w.w;
        }
        float4 b = *(const float4*)(bias + base);
        acc.x += b.x; acc.y += b.y; acc.z += b.z; acc.w += b.w;
        *(float4*)(out + (long long)r * out_f + base) = acc;
    }
}

static size_t align_up(size_t x, size_t a) { return (x + a - 1) & ~(a - 1); }

extern "C" void kernel_launch(void* const* d_in, const int* in_sizes, int n_in,
                              void* d_out, int out_size, void* d_ws, size_t ws_size,
                              hipStream_t stream) {
    const float* values = (const float*)d_in[0];
    const float* weight = (const float*)d_in[1];
    const float* bias   = (const float*)d_in[2];
    const int*   rows   = (const int*)d_in[3];
    const int*   cols   = (const int*)d_in[4];

    const int nnz = in_sizes[0];
    const long long wtotal = in_sizes[1];
    const int out_f = in_sizes[2];
    const int n_rows = out_size / out_f;
    float* out = (float*)d_out;

    // ws layout: wf16[wtotal] | counts[n_rows] | offsets[n_rows+1] | cursor[n_rows] | pairs[nnz]
    size_t off_wf16 = 0;
    size_t off_counts = align_up(off_wf16 + (size_t)wtotal * sizeof(__half), 256);
    size_t off_offsets = off_counts + (size_t)n_rows * sizeof(int);
    size_t off_cursor = off_offsets + (size_t)(n_rows + 1) * sizeof(int);
    size_t off_pairs = align_up(off_cursor + (size_t)n_rows * sizeof(int), 256);
    size_t need = off_pairs + (size_t)nnz * sizeof(int2);

    if (ws_size >= need && out_f == 512 && (wtotal % 16) == 0) {
        char* ws = (char*)d_ws;
        __half* wf16 = (__half*)(ws + off_wf16);
        int* counts = (int*)(ws + off_counts);
        int* offsets = (int*)(ws + off_offsets);
        int* cursor = (int*)(ws + off_cursor);
        int2* pairs = (int2*)(ws + off_pairs);

        hipMemsetAsync(counts, 0, (size_t)n_rows * sizeof(int), stream);

        long long ngroups16 = wtotal / 16;
        long long needed = (ngroups16 > (long long)(nnz / 4 + 1)) ? ngroups16
                                                                  : (long long)(nnz / 4 + 1);
        int cc_blocks = (int)((needed + 255) / 256);
        convert_count_kernel<<<cc_blocks, 256, 0, stream>>>(weight, wf16, ngroups16,
                                                            rows, counts, nnz);
        scan_kernel<<<1, 256, 0, stream>>>(counts, offsets, cursor, n_rows);
        int sc_blocks = (nnz / 4 + 1 + 255) / 256;
        scatter_pairs_kernel<<<sc_blocks, 256, 0, stream>>>(rows, cols, values, cursor,
                                                            pairs, nnz);
        accum_f16_kernel<<<n_rows, 256, 0, stream>>>(wf16, bias, offsets, pairs,
                                                     out, out_f);
    } else {
        // f32 fallback: counts | offsets | cursor | perm
        int* counts = (int*)d_ws;
        int* offsets = counts + n_rows;
        int* cursor = offsets + n_rows + 1;
        int* perm = cursor + n_rows;
        hipMemsetAsync(counts, 0, (size_t)n_rows * sizeof(int), stream);
        int blocks = (nnz + 255) / 256;
        count_rows_kernel<<<blocks, 256, 0, stream>>>(rows, counts, nnz);
        scan_kernel<<<1, 256, 0, stream>>>(counts, offsets, cursor, n_rows);
        scatter_kernel<<<blocks, 256, 0, stream>>>(rows, cursor, perm, nnz);
        accum_kernel<<<n_rows, 128, 0, stream>>>(values, weight, bias, cols,
                                                 offsets, perm, out, out_f);
    }
}